// Round 15
// baseline (528.704 us; speedup 1.0000x reference)
//
#include <hip/hip_runtime.h>
#include <hip/hip_bf16.h>

#define N_NODES 100000
#define N_EDGES 3200000
#define N_GRAPHS 125
#define D 64
#define NB 800          // buckets
#define BW 125          // nodes per bucket (NB*BW == N_NODES)
#define CAP 4608        // max edges per bucket (mean 4000, sigma ~63; mean+9.6σ)
#define SC_WGS 400      // bucket_scatter workgroups
#define SC_EPW 8000     // edges per scatter wg (400*8000 == N_EDGES)

typedef __bf16 bf16x8 __attribute__((ext_vector_type(8)));
typedef float f32x4 __attribute__((ext_vector_type(4)));
typedef unsigned u32x4 __attribute__((ext_vector_type(4)));

__device__ __forceinline__ float bf_lo(unsigned u) { return __uint_as_float(u << 16); }
__device__ __forceinline__ float bf_hi(unsigned u) { return __uint_as_float(u & 0xffff0000u); }
// RNE float->bf16 bits (matches __float2bfloat16 for normal inputs)
__device__ __forceinline__ unsigned short f2bf(float f) {
    unsigned u = __float_as_uint(f);
    return (unsigned short)((u + 0x7fffu + ((u >> 16) & 1u)) >> 16);
}

// ---------- CSR build (bucketed, LDS-atomic, 4-byte packed pairs) ----------
// packed edge word: src<<7 | (dst - bucket*BW)   [src<2^17, local dst<125<2^7]

// partition edges into NB dst-range buckets; bcursor is RELATIVE (pre-zeroed)
__global__ void bucket_scatter(const int* __restrict__ src, const int* __restrict__ dst,
                               int* __restrict__ bcursor, unsigned* __restrict__ pairs) {
    __shared__ int bins[NB];
    int wg = blockIdx.x, t = threadIdx.x;
    int e0 = wg * SC_EPW, e1 = e0 + SC_EPW;
    for (int i = t; i < NB; i += 256) bins[i] = 0;
    __syncthreads();
    for (int i = e0 + t; i < e1; i += 256)
        atomicAdd(&bins[dst[i] / BW], 1);
    __syncthreads();
    for (int i = t; i < NB; i += 256) {
        int c = bins[i];
        bins[i] = i * CAP + (c ? atomicAdd(&bcursor[i], c) : 0);
    }
    __syncthreads();
    for (int i = e0 + t; i < e1; i += 256) {
        int s = src[i], d = dst[i];
        int b = d / BW;
        int pos = atomicAdd(&bins[b], 1);
        __builtin_nontemporal_store(((unsigned)s << 7) | (unsigned)(d - b * BW), &pairs[pos]);
    }
}

// per-bucket: histogram -> deg/dis, in-LDS exclusive scan -> row_start (bucket-padded),
// then CSR fill with LDS cursors. Replaces hist + global scan + fill.
__global__ void bucket_build(const unsigned* __restrict__ pairs, const int* __restrict__ bcursor,
                             int* __restrict__ deg, float* __restrict__ dis,
                             int* __restrict__ row_start, int* __restrict__ csr) {
    __shared__ int h[BW];
    __shared__ int sc[128];
    __shared__ int cur[BW];
    int b = blockIdx.x, t = threadIdx.x;  // 256 threads
    int nb = b * BW;
    for (int i = t; i < BW; i += 256) h[i] = 0;
    __syncthreads();
    int base = b * CAP, n = bcursor[b];
    for (int i = t; i < n; i += 256)
        atomicAdd(&h[__builtin_nontemporal_load(&pairs[base + i]) & 127u], 1);
    __syncthreads();
    int own = 0;
    if (t < 128) {
        own = (t < BW) ? h[t] : 0;
        sc[t] = own;
    }
    if (t < BW) {
        deg[nb + t] = own;
        dis[nb + t] = rsqrtf((float)own + 1.0f);
    }
    __syncthreads();
    for (int off = 1; off < 128; off <<= 1) {
        int v = (t >= off && t < 128) ? sc[t - off] : 0;
        __syncthreads();
        if (t < 128) sc[t] += v;
        __syncthreads();
    }
    if (t < BW) {
        int rs = base + sc[t] - own;   // bucket-padded: base + exclusive local prefix
        row_start[nb + t] = rs;
        cur[t] = rs;
    }
    __syncthreads();
    for (int i = t; i < n; i += 256) {
        unsigned p = __builtin_nontemporal_load(&pairs[base + i]);
        int pos = atomicAdd(&cur[p & 127u], 1);
        __builtin_nontemporal_store((int)(p >> 7), &csr[pos]);
    }
}

// ---------- compute ----------

// x (fp32) -> xb (bf16), 4 elems/thread
__global__ void cast_kernel(const float* __restrict__ x, unsigned short* __restrict__ xb) {
    int i = blockIdx.x * blockDim.x + threadIdx.x;
    if (i < N_NODES * D / 4) {
        float4 v = ((const float4*)x)[i];
        union { unsigned short s[4]; uint2 u; } p;
        p.s[0] = f2bf(v.x); p.s[1] = f2bf(v.y); p.s[2] = f2bf(v.z); p.s[3] = f2bf(v.w);
        ((uint2*)xb)[i] = p.u;
    }
}

// MFMA GEMM: Y[100000x64] = X[100000x64] @ W[64x64], bf16 in/out, fp32 accumulate.
// NOTE: no __restrict__ on Xb/Y — layer 1 runs IN-PLACE (Y == Xb). Safe: each
// 16-row tile is read and written only by its own wave, loads precede stores.
__global__ void mfma_gemm(const unsigned short* Xb, const float* __restrict__ W,
                          unsigned short* Y) {
    int lane = threadIdx.x & 63;
    int wid  = (blockIdx.x * blockDim.x + threadIdx.x) >> 6;
    int nwav = (gridDim.x * blockDim.x) >> 6;
    int nl = lane & 15;         // col within tile / row within A-tile
    int kq = lane >> 4;         // quad
    int kb = kq * 8;            // k base within K-step
    union BV { unsigned short s[8]; bf16x8 v; } b0[4], b1[4];
#pragma unroll
    for (int nt = 0; nt < 4; ++nt) {
        int n = nt * 16 + nl;
#pragma unroll
        for (int j = 0; j < 8; ++j) {
            b0[nt].s[j] = f2bf(W[(kb + j) * 64 + n]);
            b1[nt].s[j] = f2bf(W[(32 + kb + j) * 64 + n]);
        }
    }
    const uint4* X4 = (const uint4*)Xb;   // 8 uint4 per 64-elem row
    for (int t = wid; t < N_NODES / 16; t += nwav) {
        int m0 = t * 16;
        uint4 a0u = X4[(size_t)(m0 + nl) * 8 + kq];
        uint4 a1u = X4[(size_t)(m0 + nl) * 8 + 4 + kq];
        bf16x8 a0 = __builtin_bit_cast(bf16x8, a0u);
        bf16x8 a1 = __builtin_bit_cast(bf16x8, a1u);
        f32x4 acc[4];
#pragma unroll
        for (int nt = 0; nt < 4; ++nt) {
            acc[nt] = (f32x4){0.0f, 0.0f, 0.0f, 0.0f};
            acc[nt] = __builtin_amdgcn_mfma_f32_16x16x32_bf16(a0, b0[nt].v, acc[nt], 0, 0, 0);
            acc[nt] = __builtin_amdgcn_mfma_f32_16x16x32_bf16(a1, b1[nt].v, acc[nt], 0, 0, 0);
        }
        int rbase = m0 + kq * 4;   // D: row = quad*4 + reg, col = nl
#pragma unroll
        for (int nt = 0; nt < 4; ++nt) {
            int n = nt * 16 + nl;
#pragma unroll
            for (int r = 0; r < 4; ++r)
                Y[(size_t)(rbase + r) * 64 + n] = f2bf(acc[nt][r]);
        }
    }
}

// one wave per dst node; 8 lanes per edge, each lane loads uint4 = 8 bf16 feats.
// bucket-padded CSR: base = row_start[v], n = deg[v].
__global__ void gather_kernel(const unsigned short* __restrict__ Hb, const int* __restrict__ csr,
                              const int* __restrict__ row_start, const int* __restrict__ deg,
                              const float* __restrict__ dis,
                              const float* __restrict__ bias, void* __restrict__ Out,
                              int do_relu, int out_bf16) {
    int v    = (blockIdx.x * blockDim.x + threadIdx.x) >> 6;
    int lane = threadIdx.x & 63;
    int oct  = lane >> 3;
    int l8   = lane & 7;
    if (v >= N_NODES) return;
    int base = row_start[v];
    int n = deg[v];
    float disv = dis[v];
    const uint4* H4 = (const uint4*)Hb;

    float a0 = 0, a1 = 0, a2 = 0, a3 = 0, a4 = 0, a5 = 0, a6 = 0, a7 = 0;
    if (oct == 0) {
        uint4 hv = H4[(size_t)v * 8 + l8];
        float ss = disv * disv;
        float4 blo = ((const float4*)bias)[2 * l8];
        float4 bhi = ((const float4*)bias)[2 * l8 + 1];
        a0 = fmaf(bf_lo(hv.x), ss, blo.x); a1 = fmaf(bf_hi(hv.x), ss, blo.y);
        a2 = fmaf(bf_lo(hv.y), ss, blo.z); a3 = fmaf(bf_hi(hv.y), ss, blo.w);
        a4 = fmaf(bf_lo(hv.z), ss, bhi.x); a5 = fmaf(bf_hi(hv.z), ss, bhi.y);
        a6 = fmaf(bf_lo(hv.w), ss, bhi.z); a7 = fmaf(bf_hi(hv.w), ss, bhi.w);
    }

    for (int c = 0; c < n; c += 64) {
        int m = min(64, n - c);
        int sl = 0; float dl = 0.0f;
        if (lane < m) {
            sl = __builtin_nontemporal_load(&csr[base + c + lane]);
            dl = dis[sl];
        }
        int mp = (m + 7) >> 3;
#pragma unroll 4
        for (int t = 0; t < mp; ++t) {
            int eidx = 8 * t + oct;
            int ssrc  = __shfl(sl, eidx);
            float nrm = __shfl(dl, eidx) * disv;
            uint4 hv = H4[(size_t)ssrc * 8 + l8];
            a0 = fmaf(bf_lo(hv.x), nrm, a0); a1 = fmaf(bf_hi(hv.x), nrm, a1);
            a2 = fmaf(bf_lo(hv.y), nrm, a2); a3 = fmaf(bf_hi(hv.y), nrm, a3);
            a4 = fmaf(bf_lo(hv.z), nrm, a4); a5 = fmaf(bf_hi(hv.z), nrm, a5);
            a6 = fmaf(bf_lo(hv.w), nrm, a6); a7 = fmaf(bf_hi(hv.w), nrm, a7);
        }
    }
#pragma unroll
    for (int off = 8; off <= 32; off <<= 1) {
        a0 += __shfl_xor(a0, off); a1 += __shfl_xor(a1, off);
        a2 += __shfl_xor(a2, off); a3 += __shfl_xor(a3, off);
        a4 += __shfl_xor(a4, off); a5 += __shfl_xor(a5, off);
        a6 += __shfl_xor(a6, off); a7 += __shfl_xor(a7, off);
    }
    if (oct == 0) {
        if (do_relu) {
            a0 = fmaxf(a0, 0.0f); a1 = fmaxf(a1, 0.0f); a2 = fmaxf(a2, 0.0f); a3 = fmaxf(a3, 0.0f);
            a4 = fmaxf(a4, 0.0f); a5 = fmaxf(a5, 0.0f); a6 = fmaxf(a6, 0.0f); a7 = fmaxf(a7, 0.0f);
        }
        if (out_bf16) {
            union { unsigned short s[8]; u32x4 u; } p;
            p.s[0] = f2bf(a0); p.s[1] = f2bf(a1); p.s[2] = f2bf(a2); p.s[3] = f2bf(a3);
            p.s[4] = f2bf(a4); p.s[5] = f2bf(a5); p.s[6] = f2bf(a6); p.s[7] = f2bf(a7);
            __builtin_nontemporal_store(p.u, (u32x4*)Out + (size_t)v * 8 + l8);
        } else {
            f32x4* o = (f32x4*)Out + (size_t)v * 16 + 2 * l8;
            f32x4 v0 = {a0, a1, a2, a3};
            f32x4 v1 = {a4, a5, a6, a7};
            __builtin_nontemporal_store(v0, &o[0]);
            __builtin_nontemporal_store(v1, &o[1]);
        }
    }
}

// Y[r][c] = sum_k X[r][k] * W[k][c] (+ bias) — fp32, tiny head GEMM only.
__global__ void gemm_kernel(const float* __restrict__ X, const float* __restrict__ W,
                            const float* __restrict__ bias, float* __restrict__ Y,
                            int nrows) {
    __shared__ float Ws[64][64];
    for (int i = threadIdx.x; i < 64 * 64; i += 256)
        Ws[i >> 6][i & 63] = W[i];
    __syncthreads();
    int c  = threadIdx.x & 63;
    int rl = threadIdx.x >> 6;
    int r  = blockIdx.x * 4 + rl;
    if (r < nrows) {
        const float* xr = X + (size_t)r * D;
        float acc = bias ? bias[c] : 0.0f;
#pragma unroll
        for (int k = 0; k < 64; ++k)
            acc = fmaf(xr[k], Ws[k][c], acc);
        Y[(size_t)r * D + c] = acc;
    }
}

// one block per graph: mean over contiguous node segment [ptr[g], ptr[g+1])
__global__ void pool_kernel(const float* __restrict__ H, const int* __restrict__ ptr,
                            float* __restrict__ out) {
    int g = blockIdx.x;
    int start = ptr[g], end = ptr[g + 1];
    int lane  = threadIdx.x & 63;
    int chunk = threadIdx.x >> 6;
    float acc = 0.0f;
    for (int r = start + chunk; r < end; r += 4)
        acc += H[(size_t)r * D + lane];
    __shared__ float tmp[4][64];
    tmp[chunk][lane] = acc;
    __syncthreads();
    if (threadIdx.x < 64) {
        float s = tmp[0][lane] + tmp[1][lane] + tmp[2][lane] + tmp[3][lane];
        out[g * D + lane] = s / (float)(end - start);
    }
}

extern "C" void kernel_launch(void* const* d_in, const int* in_sizes, int n_in,
                              void* d_out, int out_size, void* d_ws, size_t ws_size,
                              hipStream_t stream) {
    const float* x   = (const float*)d_in[0];
    const int*   ei  = (const int*)d_in[1];
    const int*   src = ei;
    const int*   dst = ei + N_EDGES;
    const int*   ptr = (const int*)d_in[2];
    const float* W1  = (const float*)d_in[3];
    const float* b1  = (const float*)d_in[4];
    const float* W2  = (const float*)d_in[5];
    const float* b2  = (const float*)d_in[6];
    const float* Wf  = (const float*)d_in[7];
    const float* bfp = (const float*)d_in[8];
    float* out = (float*)d_out;

    // workspace layout (4-byte units) — ALL REGIONS DISJOINT (R9-R13 had
    // Ab/Hb/Bf overlapping: a latent race diluted by the mean-pool; fixed here)
    int*   deg       = (int*)d_ws;                   // 100352
    int*   row_start = deg + 100352;                 // 100352
    int*   bcursor   = row_start + 100352;           // 1024
    float* P         = (float*)(bcursor + 1024);     // 8192 (125*64 used)
    float* dis       = P + 8192;                     // 100352
    int*   csr       = (int*)(dis + 100352);         // NB*CAP = 3,686,400 (bucket-padded)
    float* R         = (float*)(csr + 3686400);
    unsigned short* Ab = (unsigned short*)R;         // bf16 N*64 = 3.2M words
    unsigned short* Hb = (unsigned short*)(R + 3200000);   // bf16 N*64 = 3.2M words
    float* Bf        = R + 6400000;                  // fp32 N*64 = 6.4M words
    unsigned* pairs  = (unsigned*)Bf;                // NB*CAP = 3.69M words <= Bf (dead before gather2)

    // cast x -> Ab (bf16); gemm1 then runs IN-PLACE on Ab
    cast_kernel<<<(N_NODES * D / 4 + 255) / 256, 256, 0, stream>>>(x, Ab);

    // --- CSR build ---
    hipMemsetAsync(bcursor, 0, NB * sizeof(int), stream);
    bucket_scatter<<<SC_WGS, 256, 0, stream>>>(src, dst, bcursor, pairs);
    bucket_build<<<NB, 256, 0, stream>>>(pairs, bcursor, deg, dis, row_start, csr);

    const int grid4 = (N_NODES + 3) / 4;

    // layer 1: Ab = bf16(Ab @ W1) in-place ; Hb = bf16(relu(gather(Ab) + Ab*dis^2 + b1))
    mfma_gemm<<<782, 256, 0, stream>>>(Ab, W1, Ab);
    gather_kernel<<<grid4, 256, 0, stream>>>(Ab, csr, row_start, deg, dis, b1, Hb, 1, 1);

    // layer 2: Ab = bf16(Hb @ W2) ; Bf = fp32(relu(gather(Ab) + Ab*dis^2 + b2))
    mfma_gemm<<<782, 256, 0, stream>>>(Hb, W2, Ab);
    gather_kernel<<<grid4, 256, 0, stream>>>(Ab, csr, row_start, deg, dis, b2, Bf, 1, 0);

    // head: pool first (mean commutes with linear head), then tiny fp32 GEMM
    pool_kernel<<<N_GRAPHS, 256, 0, stream>>>(Bf, ptr, P);
    gemm_kernel<<<(N_GRAPHS + 3) / 4, 256, 0, stream>>>(P, Wf, bfp, out, N_GRAPHS);
}

// Round 16
// 358.952 us; speedup vs baseline: 1.4729x; 1.4729x over previous
//
#include <hip/hip_runtime.h>
#include <hip/hip_bf16.h>

#define N_NODES 100000
#define N_EDGES 3200000
#define N_GRAPHS 125
#define D 64
#define NB 800          // buckets
#define BW 125          // nodes per bucket (NB*BW == N_NODES)
#define CAP 4608        // max edges per bucket (mean 4000, sigma ~63; mean+9.6σ)
#define SC_WGS 400      // bucket_scatter workgroups
#define SC_EPW 8000     // edges per scatter wg (400*8000 == N_EDGES)

typedef __bf16 bf16x8 __attribute__((ext_vector_type(8)));
typedef float f32x4 __attribute__((ext_vector_type(4)));

__device__ __forceinline__ float bf_lo(unsigned u) { return __uint_as_float(u << 16); }
__device__ __forceinline__ float bf_hi(unsigned u) { return __uint_as_float(u & 0xffff0000u); }
// RNE float->bf16 bits (matches __float2bfloat16 for normal inputs)
__device__ __forceinline__ unsigned short f2bf(float f) {
    unsigned u = __float_as_uint(f);
    return (unsigned short)((u + 0x7fffu + ((u >> 16) & 1u)) >> 16);
}

// ---------- CSR build (bucketed, LDS-atomic, 4-byte packed pairs) ----------
// packed edge word: src<<7 | (dst - bucket*BW)   [src<2^17, local dst<125<2^7]
// NOTE (R15 lesson): NO nontemporal hints anywhere — pairs/csr are produced and
// consumed within the same few-hundred-µs window, so L2 write-coalescing and
// read-hits are doing real work; nt bypassed them and cost +150 µs.

// partition edges into NB dst-range buckets; bcursor is RELATIVE (pre-zeroed)
__global__ void bucket_scatter(const int* __restrict__ src, const int* __restrict__ dst,
                               int* __restrict__ bcursor, unsigned* __restrict__ pairs) {
    __shared__ int bins[NB];
    int wg = blockIdx.x, t = threadIdx.x;
    int e0 = wg * SC_EPW, e1 = e0 + SC_EPW;
    for (int i = t; i < NB; i += 256) bins[i] = 0;
    __syncthreads();
    for (int i = e0 + t; i < e1; i += 256)
        atomicAdd(&bins[dst[i] / BW], 1);
    __syncthreads();
    for (int i = t; i < NB; i += 256) {
        int c = bins[i];
        bins[i] = i * CAP + (c ? atomicAdd(&bcursor[i], c) : 0);
    }
    __syncthreads();
    for (int i = e0 + t; i < e1; i += 256) {
        int s = src[i], d = dst[i];
        int b = d / BW;
        int pos = atomicAdd(&bins[b], 1);
        pairs[pos] = ((unsigned)s << 7) | (unsigned)(d - b * BW);
    }
}

// per-bucket: histogram -> deg/dis, in-LDS exclusive scan -> row_start (bucket-padded),
// then CSR fill with LDS cursors. Replaces hist + global scan + fill.
__global__ void bucket_build(const unsigned* __restrict__ pairs, const int* __restrict__ bcursor,
                             int* __restrict__ deg, float* __restrict__ dis,
                             int* __restrict__ row_start, int* __restrict__ csr) {
    __shared__ int h[BW];
    __shared__ int sc[128];
    __shared__ int cur[BW];
    int b = blockIdx.x, t = threadIdx.x;  // 256 threads
    int nb = b * BW;
    for (int i = t; i < BW; i += 256) h[i] = 0;
    __syncthreads();
    int base = b * CAP, n = bcursor[b];
    for (int i = t; i < n; i += 256)
        atomicAdd(&h[pairs[base + i] & 127u], 1);
    __syncthreads();
    int own = 0;
    if (t < 128) {
        own = (t < BW) ? h[t] : 0;
        sc[t] = own;
    }
    if (t < BW) {
        deg[nb + t] = own;
        dis[nb + t] = rsqrtf((float)own + 1.0f);
    }
    __syncthreads();
    for (int off = 1; off < 128; off <<= 1) {
        int v = (t >= off && t < 128) ? sc[t - off] : 0;
        __syncthreads();
        if (t < 128) sc[t] += v;
        __syncthreads();
    }
    if (t < BW) {
        int rs = base + sc[t] - own;   // bucket-padded: base + exclusive local prefix
        row_start[nb + t] = rs;
        cur[t] = rs;
    }
    __syncthreads();
    for (int i = t; i < n; i += 256) {
        unsigned p = pairs[base + i];
        int pos = atomicAdd(&cur[p & 127u], 1);
        csr[pos] = (int)(p >> 7);
    }
}

// ---------- compute ----------

// x (fp32) -> xb (bf16), 4 elems/thread
__global__ void cast_kernel(const float* __restrict__ x, unsigned short* __restrict__ xb) {
    int i = blockIdx.x * blockDim.x + threadIdx.x;
    if (i < N_NODES * D / 4) {
        float4 v = ((const float4*)x)[i];
        union { unsigned short s[4]; uint2 u; } p;
        p.s[0] = f2bf(v.x); p.s[1] = f2bf(v.y); p.s[2] = f2bf(v.z); p.s[3] = f2bf(v.w);
        ((uint2*)xb)[i] = p.u;
    }
}

// MFMA GEMM: Y[100000x64] = X[100000x64] @ W[64x64], bf16 in/out, fp32 accumulate.
// NOTE: no __restrict__ on Xb/Y — layer 1 runs IN-PLACE (Y == Xb). Safe: each
// 16-row tile is read and written only by its own wave, loads precede stores.
__global__ void mfma_gemm(const unsigned short* Xb, const float* __restrict__ W,
                          unsigned short* Y) {
    int lane = threadIdx.x & 63;
    int wid  = (blockIdx.x * blockDim.x + threadIdx.x) >> 6;
    int nwav = (gridDim.x * blockDim.x) >> 6;
    int nl = lane & 15;         // col within tile / row within A-tile
    int kq = lane >> 4;         // quad
    int kb = kq * 8;            // k base within K-step
    union BV { unsigned short s[8]; bf16x8 v; } b0[4], b1[4];
#pragma unroll
    for (int nt = 0; nt < 4; ++nt) {
        int n = nt * 16 + nl;
#pragma unroll
        for (int j = 0; j < 8; ++j) {
            b0[nt].s[j] = f2bf(W[(kb + j) * 64 + n]);
            b1[nt].s[j] = f2bf(W[(32 + kb + j) * 64 + n]);
        }
    }
    const uint4* X4 = (const uint4*)Xb;   // 8 uint4 per 64-elem row
    for (int t = wid; t < N_NODES / 16; t += nwav) {
        int m0 = t * 16;
        uint4 a0u = X4[(size_t)(m0 + nl) * 8 + kq];
        uint4 a1u = X4[(size_t)(m0 + nl) * 8 + 4 + kq];
        bf16x8 a0 = __builtin_bit_cast(bf16x8, a0u);
        bf16x8 a1 = __builtin_bit_cast(bf16x8, a1u);
        f32x4 acc[4];
#pragma unroll
        for (int nt = 0; nt < 4; ++nt) {
            acc[nt] = (f32x4){0.0f, 0.0f, 0.0f, 0.0f};
            acc[nt] = __builtin_amdgcn_mfma_f32_16x16x32_bf16(a0, b0[nt].v, acc[nt], 0, 0, 0);
            acc[nt] = __builtin_amdgcn_mfma_f32_16x16x32_bf16(a1, b1[nt].v, acc[nt], 0, 0, 0);
        }
        int rbase = m0 + kq * 4;   // D: row = quad*4 + reg, col = nl
#pragma unroll
        for (int nt = 0; nt < 4; ++nt) {
            int n = nt * 16 + nl;
#pragma unroll
            for (int r = 0; r < 4; ++r)
                Y[(size_t)(rbase + r) * 64 + n] = f2bf(acc[nt][r]);
        }
    }
}

// one wave per dst node; 8 lanes per edge, each lane loads uint4 = 8 bf16 feats.
// bucket-padded CSR: base = row_start[v], n = deg[v].
__global__ void gather_kernel(const unsigned short* __restrict__ Hb, const int* __restrict__ csr,
                              const int* __restrict__ row_start, const int* __restrict__ deg,
                              const float* __restrict__ dis,
                              const float* __restrict__ bias, void* __restrict__ Out,
                              int do_relu, int out_bf16) {
    int v    = (blockIdx.x * blockDim.x + threadIdx.x) >> 6;
    int lane = threadIdx.x & 63;
    int oct  = lane >> 3;
    int l8   = lane & 7;
    if (v >= N_NODES) return;
    int base = row_start[v];
    int n = deg[v];
    float disv = dis[v];
    const uint4* H4 = (const uint4*)Hb;

    float a0 = 0, a1 = 0, a2 = 0, a3 = 0, a4 = 0, a5 = 0, a6 = 0, a7 = 0;
    if (oct == 0) {
        uint4 hv = H4[(size_t)v * 8 + l8];
        float ss = disv * disv;
        float4 blo = ((const float4*)bias)[2 * l8];
        float4 bhi = ((const float4*)bias)[2 * l8 + 1];
        a0 = fmaf(bf_lo(hv.x), ss, blo.x); a1 = fmaf(bf_hi(hv.x), ss, blo.y);
        a2 = fmaf(bf_lo(hv.y), ss, blo.z); a3 = fmaf(bf_hi(hv.y), ss, blo.w);
        a4 = fmaf(bf_lo(hv.z), ss, bhi.x); a5 = fmaf(bf_hi(hv.z), ss, bhi.y);
        a6 = fmaf(bf_lo(hv.w), ss, bhi.z); a7 = fmaf(bf_hi(hv.w), ss, bhi.w);
    }

    for (int c = 0; c < n; c += 64) {
        int m = min(64, n - c);
        int sl = 0; float dl = 0.0f;
        if (lane < m) { sl = csr[base + c + lane]; dl = dis[sl]; }
        int mp = (m + 7) >> 3;
#pragma unroll 4
        for (int t = 0; t < mp; ++t) {
            int eidx = 8 * t + oct;
            int ssrc  = __shfl(sl, eidx);
            float nrm = __shfl(dl, eidx) * disv;
            uint4 hv = H4[(size_t)ssrc * 8 + l8];
            a0 = fmaf(bf_lo(hv.x), nrm, a0); a1 = fmaf(bf_hi(hv.x), nrm, a1);
            a2 = fmaf(bf_lo(hv.y), nrm, a2); a3 = fmaf(bf_hi(hv.y), nrm, a3);
            a4 = fmaf(bf_lo(hv.z), nrm, a4); a5 = fmaf(bf_hi(hv.z), nrm, a5);
            a6 = fmaf(bf_lo(hv.w), nrm, a6); a7 = fmaf(bf_hi(hv.w), nrm, a7);
        }
    }
#pragma unroll
    for (int off = 8; off <= 32; off <<= 1) {
        a0 += __shfl_xor(a0, off); a1 += __shfl_xor(a1, off);
        a2 += __shfl_xor(a2, off); a3 += __shfl_xor(a3, off);
        a4 += __shfl_xor(a4, off); a5 += __shfl_xor(a5, off);
        a6 += __shfl_xor(a6, off); a7 += __shfl_xor(a7, off);
    }
    if (oct == 0) {
        if (do_relu) {
            a0 = fmaxf(a0, 0.0f); a1 = fmaxf(a1, 0.0f); a2 = fmaxf(a2, 0.0f); a3 = fmaxf(a3, 0.0f);
            a4 = fmaxf(a4, 0.0f); a5 = fmaxf(a5, 0.0f); a6 = fmaxf(a6, 0.0f); a7 = fmaxf(a7, 0.0f);
        }
        if (out_bf16) {
            union { unsigned short s[8]; uint4 u; } p;
            p.s[0] = f2bf(a0); p.s[1] = f2bf(a1); p.s[2] = f2bf(a2); p.s[3] = f2bf(a3);
            p.s[4] = f2bf(a4); p.s[5] = f2bf(a5); p.s[6] = f2bf(a6); p.s[7] = f2bf(a7);
            ((uint4*)Out)[(size_t)v * 8 + l8] = p.u;
        } else {
            float4* o = (float4*)Out + (size_t)v * 16 + 2 * l8;
            o[0] = make_float4(a0, a1, a2, a3);
            o[1] = make_float4(a4, a5, a6, a7);
        }
    }
}

// Y[r][c] = sum_k X[r][k] * W[k][c] (+ bias) — fp32, tiny head GEMM only.
__global__ void gemm_kernel(const float* __restrict__ X, const float* __restrict__ W,
                            const float* __restrict__ bias, float* __restrict__ Y,
                            int nrows) {
    __shared__ float Ws[64][64];
    for (int i = threadIdx.x; i < 64 * 64; i += 256)
        Ws[i >> 6][i & 63] = W[i];
    __syncthreads();
    int c  = threadIdx.x & 63;
    int rl = threadIdx.x >> 6;
    int r  = blockIdx.x * 4 + rl;
    if (r < nrows) {
        const float* xr = X + (size_t)r * D;
        float acc = bias ? bias[c] : 0.0f;
#pragma unroll
        for (int k = 0; k < 64; ++k)
            acc = fmaf(xr[k], Ws[k][c], acc);
        Y[(size_t)r * D + c] = acc;
    }
}

// one block per graph: mean over contiguous node segment [ptr[g], ptr[g+1])
__global__ void pool_kernel(const float* __restrict__ H, const int* __restrict__ ptr,
                            float* __restrict__ out) {
    int g = blockIdx.x;
    int start = ptr[g], end = ptr[g + 1];
    int lane  = threadIdx.x & 63;
    int chunk = threadIdx.x >> 6;
    float acc = 0.0f;
    for (int r = start + chunk; r < end; r += 4)
        acc += H[(size_t)r * D + lane];
    __shared__ float tmp[4][64];
    tmp[chunk][lane] = acc;
    __syncthreads();
    if (threadIdx.x < 64) {
        float s = tmp[0][lane] + tmp[1][lane] + tmp[2][lane] + tmp[3][lane];
        out[g * D + lane] = s / (float)(end - start);
    }
}

extern "C" void kernel_launch(void* const* d_in, const int* in_sizes, int n_in,
                              void* d_out, int out_size, void* d_ws, size_t ws_size,
                              hipStream_t stream) {
    const float* x   = (const float*)d_in[0];
    const int*   ei  = (const int*)d_in[1];
    const int*   src = ei;
    const int*   dst = ei + N_EDGES;
    const int*   ptr = (const int*)d_in[2];
    const float* W1  = (const float*)d_in[3];
    const float* b1  = (const float*)d_in[4];
    const float* W2  = (const float*)d_in[5];
    const float* b2  = (const float*)d_in[6];
    const float* Wf  = (const float*)d_in[7];
    const float* bfp = (const float*)d_in[8];
    float* out = (float*)d_out;

    // workspace layout (4-byte units) — ALL REGIONS DISJOINT
    int*   deg       = (int*)d_ws;                   // 100352
    int*   row_start = deg + 100352;                 // 100352
    int*   bcursor   = row_start + 100352;           // 1024
    float* P         = (float*)(bcursor + 1024);     // 8192 (125*64 used)
    float* dis       = P + 8192;                     // 100352
    int*   csr       = (int*)(dis + 100352);         // NB*CAP = 3,686,400 (bucket-padded)
    float* R         = (float*)(csr + 3686400);
    unsigned short* Ab = (unsigned short*)R;         // bf16 N*64 = 3.2M words
    unsigned short* Hb = (unsigned short*)(R + 3200000);   // bf16 N*64 = 3.2M words
    float* Bf        = R + 6400000;                  // fp32 N*64 = 6.4M words
    unsigned* pairs  = (unsigned*)Bf;                // NB*CAP = 3.69M words <= Bf (dead before gather2)

    // cast x -> Ab (bf16); gemm1 then runs IN-PLACE on Ab
    cast_kernel<<<(N_NODES * D / 4 + 255) / 256, 256, 0, stream>>>(x, Ab);

    // --- CSR build ---
    hipMemsetAsync(bcursor, 0, NB * sizeof(int), stream);
    bucket_scatter<<<SC_WGS, 256, 0, stream>>>(src, dst, bcursor, pairs);
    bucket_build<<<NB, 256, 0, stream>>>(pairs, bcursor, deg, dis, row_start, csr);

    const int grid4 = (N_NODES + 3) / 4;

    // layer 1: Ab = bf16(Ab @ W1) in-place ; Hb = bf16(relu(gather(Ab) + Ab*dis^2 + b1))
    mfma_gemm<<<782, 256, 0, stream>>>(Ab, W1, Ab);
    gather_kernel<<<grid4, 256, 0, stream>>>(Ab, csr, row_start, deg, dis, b1, Hb, 1, 1);

    // layer 2: Ab = bf16(Hb @ W2) ; Bf = fp32(relu(gather(Ab) + Ab*dis^2 + b2))
    mfma_gemm<<<782, 256, 0, stream>>>(Hb, W2, Ab);
    gather_kernel<<<grid4, 256, 0, stream>>>(Ab, csr, row_start, deg, dis, b2, Bf, 1, 0);

    // head: pool first (mean commutes with linear head), then tiny fp32 GEMM
    pool_kernel<<<N_GRAPHS, 256, 0, stream>>>(Bf, ptr, P);
    gemm_kernel<<<(N_GRAPHS + 3) / 4, 256, 0, stream>>>(P, Wf, bfp, out, N_GRAPHS);
}